// Round 1
// baseline (240.536 us; speedup 1.0000x reference)
//
#include <hip/hip_runtime.h>
#include <math.h>

// Causal depthwise conv1d (K=4) + SiLU, fp32.
// x: (B, L, D) contiguous, w: (D, 1, 4) contiguous, out: (B, L, D).
// out[b,l,d] = silu( sum_k w[d,k] * x[b, l-3+k, d] )  (zero-pad left)
//
// Memory-bound: each thread handles 4 consecutive channels (one float4) and
// LT consecutive l positions with a register sliding window -> read
// amplification (LT+3)/LT = 1.19x, fully coalesced 16B/lane accesses.

#define LT 16           // l-positions per thread
#define TPB 256         // threads per block (multiple of 64)

__device__ __forceinline__ float silu(float v) {
    return v / (1.0f + __expf(-v));
}

__global__ __launch_bounds__(TPB) void CausalDepthwiseConv1d_9543417332015_kernel(
    const float* __restrict__ x,
    const float* __restrict__ w,
    float* __restrict__ out,
    int L, int D4) {
    // grid: (D4/TPB, L/LT, B)
    const int d4 = blockIdx.x * TPB + threadIdx.x;   // which float4 along D
    const int l0 = blockIdx.y * LT;
    const int b  = blockIdx.z;

    const float4* __restrict__ x4 =
        reinterpret_cast<const float4*>(x) + (size_t)b * L * D4;
    float4* __restrict__ o4 =
        reinterpret_cast<float4*>(out) + (size_t)b * L * D4;
    const float4* __restrict__ w4 = reinterpret_cast<const float4*>(w);

    // weight: one float4 per channel = the 4 taps. Load 4 channels, transpose
    // to per-tap vectors (tap k multiplies x[l-3+k]).
    const float4 wa = w4[d4 * 4 + 0];
    const float4 wb = w4[d4 * 4 + 1];
    const float4 wc = w4[d4 * 4 + 2];
    const float4 wd = w4[d4 * 4 + 3];
    const float4 w0 = make_float4(wa.x, wb.x, wc.x, wd.x);  // tap 0 -> x[l-3]
    const float4 w1 = make_float4(wa.y, wb.y, wc.y, wd.y);  // tap 1 -> x[l-2]
    const float4 w2 = make_float4(wa.z, wb.z, wc.z, wd.z);  // tap 2 -> x[l-1]
    const float4 w3 = make_float4(wa.w, wb.w, wc.w, wd.w);  // tap 3 -> x[l]

    const float4 zero = make_float4(0.f, 0.f, 0.f, 0.f);
    float4 xm3 = (l0 >= 3) ? x4[(size_t)(l0 - 3) * D4 + d4] : zero;
    float4 xm2 = (l0 >= 2) ? x4[(size_t)(l0 - 2) * D4 + d4] : zero;
    float4 xm1 = (l0 >= 1) ? x4[(size_t)(l0 - 1) * D4 + d4] : zero;

#pragma unroll
    for (int i = 0; i < LT; ++i) {
        const size_t row = (size_t)(l0 + i) * D4 + d4;
        const float4 xc = x4[row];
        float4 a;
        a.x = w0.x * xm3.x + w1.x * xm2.x + w2.x * xm1.x + w3.x * xc.x;
        a.y = w0.y * xm3.y + w1.y * xm2.y + w2.y * xm1.y + w3.y * xc.y;
        a.z = w0.z * xm3.z + w1.z * xm2.z + w2.z * xm1.z + w3.z * xc.z;
        a.w = w0.w * xm3.w + w1.w * xm2.w + w2.w * xm1.w + w3.w * xc.w;
        a.x = silu(a.x);
        a.y = silu(a.y);
        a.z = silu(a.z);
        a.w = silu(a.w);
        o4[row] = a;
        xm3 = xm2;
        xm2 = xm1;
        xm1 = xc;
    }
}

extern "C" void kernel_launch(void* const* d_in, const int* in_sizes, int n_in,
                              void* d_out, int out_size, void* d_ws, size_t ws_size,
                              hipStream_t stream) {
    const float* x = (const float*)d_in[0];
    const float* w = (const float*)d_in[1];
    float* out = (float*)d_out;

    const int K = 4;
    const int D = in_sizes[1] / K;        // weight is (D,1,K) -> D = 2048
    const int L = 4096;                   // per setup_inputs
    const int B = in_sizes[0] / (L * D);  // 4
    const int D4 = D / 4;                 // 512

    dim3 grid(D4 / TPB, L / LT, B);       // (2, 256, 4)
    dim3 block(TPB);
    CausalDepthwiseConv1d_9543417332015_kernel<<<grid, block, 0, stream>>>(
        x, w, out, L, D4);
}

// Round 2
// 229.639 us; speedup vs baseline: 1.0475x; 1.0475x over previous
//
#include <hip/hip_runtime.h>
#include <math.h>

// Causal depthwise conv1d (K=4) + SiLU, fp32. x: (B,L,D), w: (D,1,4).
// out[b,l,d] = silu( sum_k w[d,k] * x[b, l-3+k, d] )
//
// Latency-bound fix vs R1: per-thread footprint shrunk to fit 64 VGPRs
// (float2 channels, LT=8, 11 preloaded rows + 2 float4 weights) so each
// SIMD holds 8 waves (occupancy was halved at VGPR=68). 8192 blocks.

#define LT 8            // l-positions per thread
#define TPB 256         // threads per block

__device__ __forceinline__ float silu(float v) {
    return v / (1.0f + __expf(-v));
}

__global__ __launch_bounds__(TPB, 8) void CausalDepthwiseConv1d_9543417332015_kernel(
    const float* __restrict__ x,
    const float* __restrict__ w,
    float* __restrict__ out,
    int L, int D2) {
    // grid: (D2/TPB, L/LT, B)
    const int d2 = blockIdx.x * TPB + threadIdx.x;   // which float2 along D
    const int l0 = blockIdx.y * LT;
    const int b  = blockIdx.z;

    const float2* __restrict__ x2 =
        reinterpret_cast<const float2*>(x) + (size_t)b * L * D2;
    float2* __restrict__ o2 =
        reinterpret_cast<float2*>(out) + (size_t)b * L * D2;
    const float4* __restrict__ w4 = reinterpret_cast<const float4*>(w);

    // two channels per thread -> two float4 tap vectors (8 VGPRs)
    const float4 wa = w4[2 * d2 + 0];
    const float4 wb = w4[2 * d2 + 1];

    // Preload the LT+3 input rows this thread needs; fully unrolled static
    // indexing -> registers, loads issued back-to-back for MLP.
    float2 r[LT + 3];
    const float2 zero = make_float2(0.f, 0.f);
    if (l0 >= 3) {  // hot path: 511/512 blocks, branch-free loads
#pragma unroll
        for (int i = 0; i < LT + 3; ++i)
            r[i] = x2[(size_t)(l0 - 3 + i) * D2 + d2];
    } else {
#pragma unroll
        for (int i = 0; i < LT + 3; ++i)
            r[i] = (l0 - 3 + i >= 0) ? x2[(size_t)(l0 - 3 + i) * D2 + d2] : zero;
    }

#pragma unroll
    for (int i = 0; i < LT; ++i) {
        float2 a;
        a.x = wa.x * r[i].x + wa.y * r[i + 1].x + wa.z * r[i + 2].x + wa.w * r[i + 3].x;
        a.y = wb.x * r[i].y + wb.y * r[i + 1].y + wb.z * r[i + 2].y + wb.w * r[i + 3].y;
        a.x = silu(a.x);
        a.y = silu(a.y);
        o2[(size_t)(l0 + i) * D2 + d2] = a;
    }
}

extern "C" void kernel_launch(void* const* d_in, const int* in_sizes, int n_in,
                              void* d_out, int out_size, void* d_ws, size_t ws_size,
                              hipStream_t stream) {
    const float* x = (const float*)d_in[0];
    const float* w = (const float*)d_in[1];
    float* out = (float*)d_out;

    const int K = 4;
    const int D = in_sizes[1] / K;        // 2048
    const int L = 4096;
    const int B = in_sizes[0] / (L * D);  // 4
    const int D2 = D / 2;                 // 1024

    dim3 grid(D2 / TPB, L / LT, B);       // (4, 512, 4) = 8192 blocks
    dim3 block(TPB);
    CausalDepthwiseConv1d_9543417332015_kernel<<<grid, block, 0, stream>>>(
        x, w, out, L, D2);
}